// Round 10
// baseline (605.747 us; speedup 1.0000x reference)
//
#include <hip/hip_runtime.h>
#include <math.h>

// AttentionPooling: B=32 S=4096 E=1024 H=16 D=64
// scores[b,h,s] = (Wk_h^T q[b,h]).x[b,s]/8 ; ctx[b,h] = Wv_h (sum_s attn x[b,s]) + bv
// kfuse3: SINGLE x read. Per (b, 256-s chunk), 16 tiles of 16 s x 1024 e resident in
// LDS: phase A (complete scores per tile, eg-split lanes + shfl reduce) -> online
// softmax stats (flash rescale) -> phase B (weighted sum from the SAME tile).
// One XOR involution sigma(j)=(j&~15)|((j&15)^((j>>4)&7)) on f4 columns makes
// ds_write / phase-A / phase-B reads all conflict-floor. p read from global (L2).
// R10 FIX: phase-A p load must use the TRUE column index k (the swizzled LDS read
// at col=eg*16+(k^egx) yields x's true column eg*16+k) — was (k^egx), mispairing
// x[e] with p[e'] on all lanes with (eg&7)!=0.

constexpr int cB = 32, cS = 4096, cE = 1024, cH = 16, cD = 64, cNC = 16;

// ws layout in floats
constexpr size_t OFF_P    = 0;                     // B*H*E   = 524288
constexpr size_t OFF_C    = OFF_P + 524288;        // B*H     = 512
constexpr size_t OFF_Q    = OFF_C + 512;           // B*E     = 32768
constexpr size_t OFF_SC   = OFF_Q + 32768;         // B*H*S   = 2097152 masked scores
constexpr size_t OFF_SM   = OFF_SC + 2097152;      // B*H*NC  = 8192 chunk max
constexpr size_t OFF_SL   = OFF_SM + 8192;         // B*H*NC  = 8192 chunk expsum
constexpr size_t OFF_MF   = OFF_SL + 8192;         // B*H     = 512 row max
constexpr size_t OFF_IL   = OFF_MF + 512;          // B*H     = 512 inv rowsum
constexpr size_t OFF_CTX  = OFF_IL + 512;          // B*E     = 32768
constexpr size_t OFF_PART = OFF_CTX + 32768;       // B*NC*H*E = 8388608
constexpr size_t OFF_Y    = OFF_PART + 8388608;    // B*H*E   = 524288

__device__ inline float wave_sum64(float v) {
#pragma unroll
  for (int m = 1; m < 64; m <<= 1) v += __shfl_xor(v, m);
  return v;
}
__device__ inline float sel4(float a0, float a1, float a2, float a3, int i) {
  return i == 0 ? a0 : (i == 1 ? a1 : (i == 2 ? a2 : a3));
}

// ---------------- kgemm32: C[32, n-tile16] = A[32,1024] @ W^T rows + bias ------------
__global__ __launch_bounds__(256) void kgemm32(const float* __restrict__ A,
                                               size_t aRowStride, int aBlk,
                                               const float* __restrict__ Wm, int wRow0,
                                               const float* __restrict__ bias,
                                               float* __restrict__ C) {
  __shared__ float a_lds[32 * 1028];
  __shared__ float red[4][16][32];
  int tid = threadIdx.x;
  int bx = blockIdx.x;
  const float* abase = A + (aBlk ? ((size_t)(bx >> 2) * 1024) : (size_t)0);
#pragma unroll 4
  for (int j = 0; j < 32; ++j) {
    float4 v = *(const float4*)(abase + (size_t)j * aRowStride + (size_t)tid * 4);
    *(float4*)(a_lds + j * 1028 + tid * 4) = v;
  }
  __syncthreads();
  int wv = tid >> 6, lane = tid & 63;
  int ng = lane >> 4, bp = lane & 15;
  float acc[4][2];
#pragma unroll
  for (int j = 0; j < 4; ++j) { acc[j][0] = 0.f; acc[j][1] = 0.f; }
  const float* w0 = Wm + (size_t)(wRow0 + bx * 16 + ng * 4) * 1024;
#pragma unroll 4
  for (int i = 0; i < 64; ++i) {
    int e4 = wv * 64 + ((i + bp) & 63);
    float4 a0 = *(const float4*)(a_lds + (bp * 2 + 0) * 1028 + e4 * 4);
    float4 a1 = *(const float4*)(a_lds + (bp * 2 + 1) * 1028 + e4 * 4);
#pragma unroll
    for (int j = 0; j < 4; ++j) {
      float4 w4 = *(const float4*)(w0 + (size_t)j * 1024 + e4 * 4);
      acc[j][0] = fmaf(w4.x, a0.x, acc[j][0]); acc[j][0] = fmaf(w4.y, a0.y, acc[j][0]);
      acc[j][0] = fmaf(w4.z, a0.z, acc[j][0]); acc[j][0] = fmaf(w4.w, a0.w, acc[j][0]);
      acc[j][1] = fmaf(w4.x, a1.x, acc[j][1]); acc[j][1] = fmaf(w4.y, a1.y, acc[j][1]);
      acc[j][1] = fmaf(w4.z, a1.z, acc[j][1]); acc[j][1] = fmaf(w4.w, a1.w, acc[j][1]);
    }
  }
#pragma unroll
  for (int j = 0; j < 4; ++j) {
    red[wv][ng * 4 + j][bp * 2 + 0] = acc[j][0];
    red[wv][ng * 4 + j][bp * 2 + 1] = acc[j][1];
  }
  __syncthreads();
#pragma unroll
  for (int t = 0; t < 2; ++t) {
    int idx = t * 256 + tid;
    int n = idx >> 5, b = idx & 31;
    float s = red[0][n][b] + red[1][n][b] + red[2][n][b] + red[3][n][b] +
              bias[bx * 16 + n];
    C[(size_t)b * 1024 + bx * 16 + n] = s;
  }
}

// ---------------- kp_gemm: p[b,h,et*256+e] = 0.125 * sum_d Wk[h*64+d,e] q[b,h*64+d] ---
__global__ __launch_bounds__(256) void kp_gemm(const float* __restrict__ w,
                                               const float* __restrict__ bvec,
                                               const float* __restrict__ q,
                                               float* __restrict__ p,
                                               float* __restrict__ cb) {
  __shared__ float w_lds[64 * 260];
  __shared__ float q_lds[32 * 65];
  int h = blockIdx.x >> 2, et = blockIdx.x & 3;
  int tid = threadIdx.x;
#pragma unroll 4
  for (int j = 0; j < 16; ++j) {
    int idx = j * 256 + tid;
    int row = idx >> 6, c4 = idx & 63;
    float4 v = *(const float4*)(w + (size_t)(1024 + h * 64 + row) * 1024 + et * 256 + c4 * 4);
    *(float4*)(w_lds + row * 260 + c4 * 4) = v;
  }
#pragma unroll
  for (int jj = 0; jj < 2; ++jj) {
    int idx = jj * 256 + tid;
    int row = idx >> 4, c4 = idx & 15;
    float4 v = *(const float4*)(q + (size_t)row * 1024 + h * 64 + c4 * 4);
    *(float4*)(q_lds + row * 65 + c4 * 4) = v;
  }
  __syncthreads();
  int b = tid & 31, eg = tid >> 5;
  float4 acc[8];
#pragma unroll
  for (int j = 0; j < 8; ++j) acc[j] = make_float4(0.f, 0.f, 0.f, 0.f);
#pragma unroll 4
  for (int d = 0; d < 64; ++d) {
    float qv = q_lds[b * 65 + d];
#pragma unroll
    for (int j = 0; j < 8; ++j) {
      float4 wv4 = *(const float4*)(w_lds + d * 260 + eg * 32 + j * 4);
      acc[j].x = fmaf(wv4.x, qv, acc[j].x);
      acc[j].y = fmaf(wv4.y, qv, acc[j].y);
      acc[j].z = fmaf(wv4.z, qv, acc[j].z);
      acc[j].w = fmaf(wv4.w, qv, acc[j].w);
    }
  }
  float* pb = p + (size_t)(b * cH + h) * cE + et * 256 + eg * 32;
#pragma unroll
  for (int j = 0; j < 8; ++j) {
    float4 o = make_float4(acc[j].x * 0.125f, acc[j].y * 0.125f,
                           acc[j].z * 0.125f, acc[j].w * 0.125f);
    *(float4*)(pb + j * 4) = o;
  }
  if (et == 0 && tid < 32) {
    int bb = tid;
    float cacc = 0.f;
    for (int d = 0; d < 64; ++d)
      cacc = fmaf(q_lds[bb * 65 + d], bvec[1024 + h * 64 + d], cacc);
    cb[bb * cH + h] = 0.125f * cacc;
  }
}

// ---------------- kfuse3: single-x-read fused scores + online softmax + wsum ---------
// grid 512 = B*16 chunks of 256 s; block 256 = 4 waves; 16 tiles of 16 s x 1024 e.
// Thread ids: wave sq = s-quad (4 s); lane l: hg = l>>4 (4 h), eg = l&15 (64-e range).
// Staging: thread (st_s = tid>>4, st_q = tid&15) holds rv[16] f4 (its quarter row).
// sigma(j) = (j&~15) | ((j&15) ^ ((j>>4)&7))  (involution on f4 column index).
__global__ __launch_bounds__(256) void kfuse3(const float* __restrict__ x,
                                              const float* __restrict__ p,
                                              const float* __restrict__ cbv,
                                              const int* __restrict__ mask,
                                              float* __restrict__ scores,
                                              float* __restrict__ statsM,
                                              float* __restrict__ statsL,
                                              float* __restrict__ part) {
  __shared__ __align__(16) float xt[16 * 1024];    // 64 KB, swizzled cols
  __shared__ __align__(16) float exl[16][20];      // ex[s][h], 16B-aligned rows (80 B)
  __shared__ float smax[4][16], ssum[4][16], scl[16];
  int bx = blockIdx.x;
  int b = bx >> 4, sc = bx & 15;
  int s0g = sc * 256;
  int tid = threadIdx.x;
  int sq = tid >> 6;
  int l = tid & 63;
  int hg = l >> 4, eg = l & 15;
  int egx = eg & 7;
  int st_s = tid >> 4, st_q = tid & 15;
  int sigB = (tid & ~15) | ((tid & 15) ^ ((tid >> 4) & 7));

  const float* xrow = x + ((size_t)b * cS + s0g) * cE;
  const float* pbase = p + (size_t)(b * cH + hg * 4) * cE;

  float4 rv[16];
  {
    const float* src = xrow + (size_t)st_s * cE + st_q * 64;
#pragma unroll
    for (int i = 0; i < 16; ++i) rv[i] = *(const float4*)(src + i * 4);
  }
  float m_run[4], l_run[4];
#pragma unroll
  for (int j = 0; j < 4; ++j) { m_run[j] = -3e38f; l_run[j] = 0.f; }
  float4 acc2[16];
#pragma unroll
  for (int h = 0; h < 16; ++h) acc2[h] = make_float4(0.f, 0.f, 0.f, 0.f);
  float4 cbl = *(const float4*)(cbv + b * cH + hg * 4);
  float cba[4] = {cbl.x, cbl.y, cbl.z, cbl.w};

#pragma unroll 1
  for (int t = 0; t < 16; ++t) {
    // ---- ds_write rv -> xt (sigma-swizzled cols); then issue next tile's loads ----
#pragma unroll
    for (int i = 0; i < 16; ++i) {
      int stidx = st_s * 256 + st_q * 16 + (i ^ (st_q & 7));
      *(float4*)(xt + stidx * 4) = rv[i];
    }
    if (t < 15) {
      const float* src = xrow + (size_t)((t + 1) * 16 + st_s) * cE + st_q * 64;
#pragma unroll
      for (int i = 0; i < 16; ++i) rv[i] = *(const float4*)(src + i * 4);
    }
    __syncthreads();   // tile ready

    // ---- phase A: partial dots over this lane's 64-e range ----
    float acc[4][4];
#pragma unroll
    for (int s = 0; s < 4; ++s)
#pragma unroll
      for (int h = 0; h < 4; ++h) acc[s][h] = 0.f;
#pragma unroll
    for (int k = 0; k < 16; ++k) {
      int col = eg * 16 + (k ^ egx);   // swizzled LDS col -> true x column eg*16+k
      float4 xv0 = *(const float4*)(xt + ((sq * 4 + 0) * 256 + col) * 4);
      float4 xv1 = *(const float4*)(xt + ((sq * 4 + 1) * 256 + col) * 4);
      float4 xv2 = *(const float4*)(xt + ((sq * 4 + 2) * 256 + col) * 4);
      float4 xv3 = *(const float4*)(xt + ((sq * 4 + 3) * 256 + col) * 4);
      // p at TRUE column eg*16+k (R10 fix: was (k^egx))
      float4 pv0 = *(const float4*)(pbase + 0 * cE + eg * 64 + k * 4);
      float4 pv1 = *(const float4*)(pbase + 1 * cE + eg * 64 + k * 4);
      float4 pv2 = *(const float4*)(pbase + 2 * cE + eg * 64 + k * 4);
      float4 pv3 = *(const float4*)(pbase + 3 * cE + eg * 64 + k * 4);
      float4 xa[4] = {xv0, xv1, xv2, xv3};
      float4 pa[4] = {pv0, pv1, pv2, pv3};
#pragma unroll
      for (int s = 0; s < 4; ++s)
#pragma unroll
        for (int h = 0; h < 4; ++h) {
          acc[s][h] = fmaf(xa[s].x, pa[h].x, acc[s][h]);
          acc[s][h] = fmaf(xa[s].y, pa[h].y, acc[s][h]);
          acc[s][h] = fmaf(xa[s].z, pa[h].z, acc[s][h]);
          acc[s][h] = fmaf(xa[s].w, pa[h].w, acc[s][h]);
        }
    }
    // eg-reduce (16 lanes) -> full scores in every lane
#pragma unroll
    for (int m = 1; m < 16; m <<= 1)
#pragma unroll
      for (int s = 0; s < 4; ++s)
#pragma unroll
        for (int h = 0; h < 4; ++h) acc[s][h] += __shfl_xor(acc[s][h], m);
    // bias + mask
#pragma unroll
    for (int s = 0; s < 4; ++s)
#pragma unroll
      for (int h = 0; h < 4; ++h) acc[s][h] += cba[h];
    {
      int4 mv = *(const int4*)(mask + (size_t)b * cS + s0g + t * 16 + sq * 4);
      if (mv.x) { acc[0][0] = -1e30f; acc[0][1] = -1e30f; acc[0][2] = -1e30f; acc[0][3] = -1e30f; }
      if (mv.y) { acc[1][0] = -1e30f; acc[1][1] = -1e30f; acc[1][2] = -1e30f; acc[1][3] = -1e30f; }
      if (mv.z) { acc[2][0] = -1e30f; acc[2][1] = -1e30f; acc[2][2] = -1e30f; acc[2][3] = -1e30f; }
      if (mv.w) { acc[3][0] = -1e30f; acc[3][1] = -1e30f; acc[3][2] = -1e30f; acc[3][3] = -1e30f; }
    }
    // tile max per h (this wave's 4 s)
    float tm[4];
#pragma unroll
    for (int h = 0; h < 4; ++h)
      tm[h] = fmaxf(fmaxf(acc[0][h], acc[1][h]), fmaxf(acc[2][h], acc[3][h]));
    int hsel = eg >> 2, ssel = eg & 3;
    if (ssel == 0) smax[sq][hg * 4 + hsel] = sel4(tm[0], tm[1], tm[2], tm[3], hsel);
    __syncthreads();   // bar1
    float mnew[4], rs[4];
#pragma unroll
    for (int h = 0; h < 4; ++h) {
      int H = hg * 4 + h;
      float wm = fmaxf(fmaxf(smax[0][H], smax[1][H]), fmaxf(smax[2][H], smax[3][H]));
      mnew[h] = fmaxf(m_run[h], wm);
      rs[h] = __expf(m_run[h] - mnew[h]);
    }
    float exv[4][4], psum[4];
#pragma unroll
    for (int h = 0; h < 4; ++h) {
      psum[h] = 0.f;
#pragma unroll
      for (int s = 0; s < 4; ++s) {
        exv[s][h] = __expf(acc[s][h] - mnew[h]);
        psum[h] += exv[s][h];
      }
    }
    // my (s,h) slot: s = sq*4+ssel, h = hg*4+hsel
    {
      float r0 = sel4(acc[0][0], acc[0][1], acc[0][2], acc[0][3], hsel);
      float r1 = sel4(acc[1][0], acc[1][1], acc[1][2], acc[1][3], hsel);
      float r2 = sel4(acc[2][0], acc[2][1], acc[2][2], acc[2][3], hsel);
      float r3 = sel4(acc[3][0], acc[3][1], acc[3][2], acc[3][3], hsel);
      float myscore = sel4(r0, r1, r2, r3, ssel);
      float e0 = sel4(exv[0][0], exv[0][1], exv[0][2], exv[0][3], hsel);
      float e1 = sel4(exv[1][0], exv[1][1], exv[1][2], exv[1][3], hsel);
      float e2 = sel4(exv[2][0], exv[2][1], exv[2][2], exv[2][3], hsel);
      float e3 = sel4(exv[3][0], exv[3][1], exv[3][2], exv[3][3], hsel);
      float myex = sel4(e0, e1, e2, e3, ssel);
      scores[(size_t)(b * cH + hg * 4 + hsel) * cS + s0g + t * 16 + sq * 4 + ssel] = myscore;
      exl[sq * 4 + ssel][hg * 4 + hsel] = myex;
    }
    if (ssel == 0) {
      ssum[sq][hg * 4 + hsel] = sel4(psum[0], psum[1], psum[2], psum[3], hsel);
      if (sq == 0) scl[hg * 4 + hsel] = sel4(rs[0], rs[1], rs[2], rs[3], hsel);
    }
    __syncthreads();   // bar2: exl/ssum/scl ready
#pragma unroll
    for (int h = 0; h < 4; ++h) {
      int H = hg * 4 + h;
      float ts = ssum[0][H] + ssum[1][H] + ssum[2][H] + ssum[3][H];
      l_run[h] = l_run[h] * rs[h] + ts;
      m_run[h] = mnew[h];
    }
    // ---- phase B: rescale + accumulate from resident tile ----
    {
      const float4* sc4 = (const float4*)scl;
      float4 s0 = sc4[0], s1 = sc4[1], s2 = sc4[2], s3 = sc4[3];
      float sca[16] = {s0.x, s0.y, s0.z, s0.w, s1.x, s1.y, s1.z, s1.w,
                       s2.x, s2.y, s2.z, s2.w, s3.x, s3.y, s3.z, s3.w};
#pragma unroll
      for (int h = 0; h < 16; ++h) {
        acc2[h].x *= sca[h]; acc2[h].y *= sca[h];
        acc2[h].z *= sca[h]; acc2[h].w *= sca[h];
      }
    }
#pragma unroll
    for (int s = 0; s < 16; ++s) {
      float4 xv = *(const float4*)(xt + (s * 256 + sigB) * 4);
      const float4* er = (const float4*)(&exl[s][0]);
      float4 e0 = er[0], e1 = er[1], e2 = er[2], e3 = er[3];
      float ea[16] = {e0.x, e0.y, e0.z, e0.w, e1.x, e1.y, e1.z, e1.w,
                      e2.x, e2.y, e2.z, e2.w, e3.x, e3.y, e3.z, e3.w};
#pragma unroll
      for (int h = 0; h < 16; ++h) {
        acc2[h].x = fmaf(ea[h], xv.x, acc2[h].x);
        acc2[h].y = fmaf(ea[h], xv.y, acc2[h].y);
        acc2[h].z = fmaf(ea[h], xv.z, acc2[h].z);
        acc2[h].w = fmaf(ea[h], xv.w, acc2[h].w);
      }
    }
    __syncthreads();   // bar3: tile consumed; next ds_write may overwrite
  }

  // chunk stats
  if (sq == 0 && (eg & 3) == 0) {
    int H = hg * 4 + (eg >> 2);
    statsM[(size_t)(b * cH + H) * cNC + sc] = sel4(m_run[0], m_run[1], m_run[2], m_run[3], eg >> 2);
    statsL[(size_t)(b * cH + H) * cNC + sc] = sel4(l_run[0], l_run[1], l_run[2], l_run[3], eg >> 2);
  }
  // part
  float* pb = part + ((size_t)(b * cNC + sc) * cH) * cE + (size_t)tid * 4;
#pragma unroll
  for (int h = 0; h < 16; ++h) *(float4*)(pb + (size_t)h * cE) = acc2[h];
}

// ---------------- k5a: y[b,h,:] = (sum_ck wgt part) * iL; emit Mf/iLf ----------------
__global__ __launch_bounds__(256) void k5a_comb(const float* __restrict__ part,
                                                const float* __restrict__ statsM,
                                                const float* __restrict__ statsL,
                                                float* __restrict__ y,
                                                float* __restrict__ Mf,
                                                float* __restrict__ iLf) {
  int b = blockIdx.x >> 4, h = blockIdx.x & 15;
  int bh = b * cH + h;
  int tid = threadIdx.x;
  float M = -3e38f;
#pragma unroll
  for (int c = 0; c < cNC; ++c) M = fmaxf(M, statsM[bh * cNC + c]);
  float L = 0.f;
  float wgt[cNC];
#pragma unroll
  for (int c = 0; c < cNC; ++c) {
    wgt[c] = __expf(statsM[bh * cNC + c] - M);
    L += statsL[bh * cNC + c] * wgt[c];
  }
  float iL = 1.0f / L;
  if (tid == 0) { Mf[bh] = M; iLf[bh] = iL; }
  float4 a = make_float4(0.f, 0.f, 0.f, 0.f);
  const float* pb = part + (size_t)b * cNC * cH * cE + (size_t)h * cE + (size_t)tid * 4;
#pragma unroll
  for (int c = 0; c < cNC; ++c) {
    float4 v = *(const float4*)(pb + (size_t)c * cH * cE);
    a.x = fmaf(v.x, wgt[c], a.x); a.y = fmaf(v.y, wgt[c], a.y);
    a.z = fmaf(v.z, wgt[c], a.z); a.w = fmaf(v.w, wgt[c], a.w);
  }
  a.x *= iL; a.y *= iL; a.z *= iL; a.w *= iL;
  *(float4*)(y + (size_t)bh * cE + (size_t)tid * 4) = a;
}

// ---------------- kmean: attn_weights[b,0,s] = mean_h exp(score - M_h)*iL_h ----------
__global__ __launch_bounds__(256) void kmean(const float* __restrict__ scores,
                                             const float* __restrict__ Mf,
                                             const float* __restrict__ iLf,
                                             float* __restrict__ out) {
  int idx = blockIdx.x * 256 + threadIdx.x;
  int b = idx >> 12, s = idx & 4095;
  float sum = 0.f;
#pragma unroll
  for (int h = 0; h < cH; ++h) {
    float v = scores[(size_t)(b * cH + h) * cS + s];
    sum += __expf(v - Mf[b * cH + h]) * iLf[b * cH + h];
  }
  out[cB * cE + (size_t)b * cS + s] = sum * (1.0f / 16.0f);
}

extern "C" void kernel_launch(void* const* d_in, const int* in_sizes, int n_in,
                              void* d_out, int out_size, void* d_ws, size_t ws_size,
                              hipStream_t stream) {
  const float* x = (const float*)d_in[0];
  const int* mask = (const int*)d_in[1];
  const float* in_proj_w = (const float*)d_in[2];
  const float* in_proj_b = (const float*)d_in[3];
  const float* out_w = (const float*)d_in[4];
  const float* out_b = (const float*)d_in[5];
  float* out = (float*)d_out;
  float* W = (float*)d_ws;

  float* p = W + OFF_P;
  float* cb = W + OFF_C;
  float* q = W + OFF_Q;
  float* scores = W + OFF_SC;
  float* statsM = W + OFF_SM;
  float* statsL = W + OFF_SL;
  float* Mf = W + OFF_MF;
  float* iLf = W + OFF_IL;
  float* ctx = W + OFF_CTX;
  float* part = W + OFF_PART;
  float* y = W + OFF_Y;

  // q[32,1024] = x[:,0,:] @ Wq^T + bq
  kgemm32<<<64, 256, 0, stream>>>(x, (size_t)cS * cE, 0, in_proj_w, 0, in_proj_b, q);
  // p + cb (Wk rows 1024..2047)
  kp_gemm<<<64, 256, 0, stream>>>(in_proj_w, in_proj_b, q, p, cb);
  // fused single-x-read scores + stats + weighted partial sums
  kfuse3<<<512, 256, 0, stream>>>(x, p, cb, mask, scores, statsM, statsL, part);
  // combine chunks -> y, emit Mf/iLf
  k5a_comb<<<512, 256, 0, stream>>>(part, statsM, statsL, y, Mf, iLf);
  // ctx[32,1024] = y_h @ Wv_h^T + bv
  kgemm32<<<64, 256, 0, stream>>>(y, (size_t)cH * cE, 1, in_proj_w, 2048,
                                  in_proj_b + 2048, ctx);
  // attn-weights mean
  kmean<<<512, 256, 0, stream>>>(scores, Mf, iLf, out);
  // out[32,1024] = ctx @ out_w^T + out_b
  kgemm32<<<64, 256, 0, stream>>>(ctx, (size_t)cE, 0, out_w, 0, out_b, out);
}